// Round 5
// baseline (240.717 us; speedup 1.0000x reference)
//
#include <hip/hip_runtime.h>

// MCANet: out = x * sigmoid(w1d[c, center] * mean_{h,w}(x[b,c,h,w]))
// The conv1x1+softmax branch in the reference is dead code (del y).
// x: (16, 512, 64, 64) f32; w1d: (512, 5) f32; center tap index = 2.
//
// Cache-policy quadrant test (r3/r4 post-mortem):
//   - PLAIN loads: x (134 MB) fits entirely in the 256 MB Infinity Cache;
//     round-3 profile proved L3 retained ~half of x across iterations
//     (FETCH 65.6 MB for 268 MB of read requests) EVEN while the plain
//     store stream thrashed it. Letting x allocate => steady-state reads
//     come from L3, not HBM.
//   - NT stores: out is never re-read; bypassing keeps the 134 MB store
//     stream from evicting x (this eviction was round-3's regression).
//   - Register pin: round-3 profile proved the compiler re-reads x for
//     the scale phase when allowed (VGPR=52 < 64 needed for the tile);
//     the asm ballast forces the 16 vf4s to stay live across the
//     reduction so the store loop consumes registers.
//
// Structure: one wave per plane, barrier-free. 16 outstanding vf4 loads
// per lane, packed accumulate, __shfl_xor butterfly (all 64 lanes end
// with the plane sum), per-lane sigmoid, immediate NT stores.

#define NC 512
#define HW 4096           // 64*64
#define PER_LANE 16       // (HW/4) vf4s / 64 lanes

typedef float vf4 __attribute__((ext_vector_type(4)));

__global__ __launch_bounds__(256) void mcanet_gate_kernel(
    const float* __restrict__ x,
    const float* __restrict__ w1d,
    float* __restrict__ out)
{
    const int wave  = threadIdx.x >> 6;
    const int lane  = threadIdx.x & 63;
    const int plane = (blockIdx.x << 2) + wave;   // b*NC + c
    const int c = plane & (NC - 1);

    // Tiny gate-weight load first: 10 KB table, cache-resident; its
    // latency hides under the 16 plane loads.
    const float wc = w1d[c * 5 + 2];

    const long long base = (long long)plane * HW;
    const vf4* __restrict__ xin = (const vf4*)(x + base);
    vf4* __restrict__ o = (vf4*)(out + base);

    // Wave covers its 16 KB plane: lane i reads vf4 (lane + 64*k),
    // i.e. 1 KB contiguous per load instruction, 16 in flight.
    // PLAIN loads: allocate x in L2/L3.
    vf4 v[PER_LANE];
    #pragma unroll
    for (int i = 0; i < PER_LANE; ++i)
        v[i] = xin[lane + (i << 6)];

    // Packed accumulate (v_pk_add_f32), then horizontal.
    vf4 acc = v[0];
    #pragma unroll
    for (int i = 1; i < PER_LANE; ++i)
        acc += v[i];
    float s = (acc.x + acc.y) + (acc.z + acc.w);

    // Pin the tile in VGPRs: the compiler may NOT rematerialize the
    // global loads after this point.
    asm volatile(""
        : "+v"(v[0]), "+v"(v[1]), "+v"(v[2]),  "+v"(v[3]),
          "+v"(v[4]), "+v"(v[5]), "+v"(v[6]),  "+v"(v[7]),
          "+v"(v[8]), "+v"(v[9]), "+v"(v[10]), "+v"(v[11]),
          "+v"(v[12]), "+v"(v[13]), "+v"(v[14]), "+v"(v[15]));

    // Butterfly: every lane ends with the full plane sum.
    #pragma unroll
    for (int off = 32; off > 0; off >>= 1)
        s += __shfl_xor(s, off, 64);

    const float zc = wc * (s * (1.0f / (float)HW));
    const float g  = 1.0f / (1.0f + __expf(-zc));

    // NT stores: out is write-once/never-read -> don't evict x from L3.
    #pragma unroll
    for (int i = 0; i < PER_LANE; ++i) {
        vf4 r = v[i] * g;
        __builtin_nontemporal_store(r, o + lane + (i << 6));
    }
}

extern "C" void kernel_launch(void* const* d_in, const int* in_sizes, int n_in,
                              void* d_out, int out_size, void* d_ws, size_t ws_size,
                              hipStream_t stream) {
    const float* x   = (const float*)d_in[0];  // (16,512,64,64)
    // d_in[1] = w1x1 (unused), d_in[2] = b1x1 (unused)
    const float* w1d = (const float*)d_in[3];  // (512,5)
    float* out = (float*)d_out;

    const int planes = 16 * NC;                // 8192 planes
    mcanet_gate_kernel<<<planes / 4, 256, 0, stream>>>(x, w1d, out);
}

// Round 6
// 227.305 us; speedup vs baseline: 1.0590x; 1.0590x over previous
//
#include <hip/hip_runtime.h>

// MCANet: out = x * sigmoid(w1d[c, center] * mean_{h,w}(x[b,c,h,w]))
// x: (16, 512, 64, 64) f32; w1d: (512, 5) f32; center tap = 2.
//
// r5 post-mortem: traffic was ALWAYS minimal (268 MB; no remat, no spill —
// tile lives in AGPRs, hence the low VGPR counts). NT+NT runs 4.1 TB/s vs
// 6.29 TB/s for a plain float4 copy: the gap is the per-wave monolithic
// load-burst -> full-latency stall -> butterfly -> store-burst structure,
// phase-aligned across the whole one-shot grid.
//
// Fix: software-pipeline 4 planes per wave with a 3-BUFFER register
// rotation. 3 buffers, not 2: re-loading into a just-stored buffer makes
// the register WAR hazard force s_waitcnt vmcnt(0) (full drain) every
// iteration; with 3 the oldest stores are 1 full FINISH old and every
// wait is a non-draining vmcnt(32). Steady state keeps ~32-48 loads +
// 16 stores in flight per wave; reads and writes mix continuously.
//
// NT on both streams (measured best arm: plain loads = 3.2 TB/s, NT = 4.1).

#define NC 512
#define HW 4096            // 64*64
#define PER_LANE 16        // (HW/4) vf4s / 64 lanes
#define NBLK 512
#define NWAVE (NBLK * 4)   // 2048 waves
#define PPW 4              // planes per wave; NWAVE*PPW = 8192 planes

typedef float vf4 __attribute__((ext_vector_type(4)));

__global__ __launch_bounds__(256) void mcanet_gate_kernel(
    const float* __restrict__ x,
    const float* __restrict__ w1d,
    float* __restrict__ out)
{
    const int lane = threadIdx.x & 63;
    const int gw   = (blockIdx.x << 2) + (threadIdx.x >> 6);

    vf4 va[PER_LANE], vb[PER_LANE], vc[PER_LANE];

// Issue 16 NT vf4 loads for plane pl into buf (1 KB/instruction, coalesced).
#define ISSUE(buf, pl)                                                        \
    do {                                                                      \
        const vf4* __restrict__ xin_ =                                        \
            (const vf4*)(x + (long long)(pl) * HW);                           \
        _Pragma("unroll")                                                     \
        for (int i_ = 0; i_ < PER_LANE; ++i_)                                 \
            buf[i_] = __builtin_nontemporal_load(xin_ + lane + (i_ << 6));    \
    } while (0)

// Reduce buf, broadcast plane sum via butterfly, gate, NT-store buf*g.
#define FINISH(buf, pl)                                                       \
    do {                                                                      \
        vf4 acc_ = buf[0];                                                    \
        _Pragma("unroll")                                                     \
        for (int i_ = 1; i_ < PER_LANE; ++i_) acc_ += buf[i_];                \
        float s_ = (acc_.x + acc_.y) + (acc_.z + acc_.w);                     \
        _Pragma("unroll")                                                     \
        for (int off_ = 32; off_ > 0; off_ >>= 1)                             \
            s_ += __shfl_xor(s_, off_, 64);                                   \
        const float wc_ = w1d[((pl) & (NC - 1)) * 5 + 2];                     \
        const float zc_ = wc_ * (s_ * (1.0f / (float)HW));                    \
        const float g_  = 1.0f / (1.0f + __expf(-zc_));                       \
        vf4* __restrict__ o_ = (vf4*)(out + (long long)(pl) * HW);            \
        _Pragma("unroll")                                                     \
        for (int i_ = 0; i_ < PER_LANE; ++i_) {                               \
            vf4 r_ = buf[i_] * g_;                                            \
            __builtin_nontemporal_store(r_, o_ + lane + (i_ << 6));           \
        }                                                                     \
    } while (0)

    const int p0 = gw;
    const int p1 = gw + NWAVE;
    const int p2 = gw + 2 * NWAVE;
    const int p3 = gw + 3 * NWAVE;

    ISSUE(va, p0);          // prologue: 2 planes in flight
    ISSUE(vb, p1);
    FINISH(va, p0);         // waits vmcnt(16); vb stays in flight
    ISSUE(vc, p2);          // fresh buffer: no WAR hazard
    FINISH(vb, p1);         // waits vmcnt(32): leaves vc loads + va stores
    ISSUE(va, p3);          // va stores are 1 FINISH old -> non-draining wait
    FINISH(vc, p2);
    FINISH(va, p3);

#undef ISSUE
#undef FINISH
}

extern "C" void kernel_launch(void* const* d_in, const int* in_sizes, int n_in,
                              void* d_out, int out_size, void* d_ws, size_t ws_size,
                              hipStream_t stream) {
    const float* x   = (const float*)d_in[0];  // (16,512,64,64)
    // d_in[1] = w1x1 (unused), d_in[2] = b1x1 (unused)
    const float* w1d = (const float*)d_in[3];  // (512,5)
    float* out = (float*)d_out;

    mcanet_gate_kernel<<<NBLK, 256, 0, stream>>>(x, w1d, out);
}